// Round 2
// baseline (108.682 us; speedup 1.0000x reference)
//
#include <hip/hip_runtime.h>
#include <hip/hip_bf16.h>

// Problem constants
#define NS    65536
#define KEXP  8
#define WID   64
#define DOUT  32
#define DIN   74
#define TM    64     // samples per tile
#define XS    104    // X row stride (u16), mult of 8 -> 16B-aligned b128 frags
#define HS    72     // H / W1t / W2t row stride (u16)
#define GX    128    // blocks per expert in MLP kernel (1 tile/block typical)
#define NB    64     // scatter blocks (NS/1024)

typedef __attribute__((ext_vector_type(8))) short short8;
typedef __attribute__((ext_vector_type(4))) float floatx4;

// f32 -> bf16 round-to-nearest-even.
__device__ __forceinline__ unsigned short f2b(float f) {
  unsigned u = __builtin_bit_cast(unsigned, f);
  u = u + 0x7FFFu + ((u >> 16) & 1u);
  return (unsigned short)(u >> 16);
}

// d_ws layout:
//   bytes [0 .. 1MB)       : bucket, u16[KEXP][NB][1024] (block-sliced, no init needed)
//   bytes [1MB .. 1MB+2KB) : hist, int[NB][KEXP]         (plain stores, no init needed)
// Memset-free and global-atomic-free: every ws word read was written earlier
// in the same launch (scatter -> mlp graph edge).

__global__ __launch_bounds__(1024) void k_scatter(const int* __restrict__ idxs,
                                                  unsigned short* __restrict__ bucket,
                                                  int* __restrict__ hist) {
  __shared__ int lc[KEXP];
  const int tid = threadIdx.x;
  const int b = blockIdx.x;
  if (tid < KEXP) lc[tid] = 0;
  __syncthreads();
  const int gid = b * 1024 + tid;
  const int e = idxs[gid];
  const int rank = atomicAdd(&lc[e], 1);          // LDS atomic
  bucket[(e << 16) + (b << 10) + rank] = (unsigned short)gid;
  __syncthreads();
  if (tid < KEXP) hist[b * KEXP + tid] = lc[tid];
}

// Binary search over the per-lane-distributed inclusive prefix (p) / counts (c).
// Returns source block sb; *lcl = local rank within that block.
__device__ __forceinline__ int seg_search(unsigned p, unsigned c, int pp, int* lcl) {
  int lo = 0, hi = NB - 1;
#pragma unroll
  for (int it = 0; it < 6; ++it) {
    const int mid = (lo + hi) >> 1;
    const unsigned pm = (unsigned)__shfl((int)p, mid, 64);
    if (pm > (unsigned)pp) hi = mid;
    else lo = mid + 1;
  }
  const unsigned base = (unsigned)__shfl((int)(p - c), lo, 64);  // exclusive prefix of sb
  *lcl = pp - (int)base;
  return lo;
}

__global__ __launch_bounds__(256) void k_mlp(
    const int* __restrict__ hist,
    const unsigned short* __restrict__ bucket,
    const float* __restrict__ pos,
    const float* __restrict__ view,
    const float* __restrict__ feat,
    const float* __restrict__ W0,
    const float* __restrict__ B0,
    const float* __restrict__ W1,
    const float* __restrict__ B1,
    const float* __restrict__ W2,
    const float* __restrict__ B2,
    float* __restrict__ out)
{
  const int e = blockIdx.y;
  const int tid = threadIdx.x;
  const int lane = tid & 63;
  const int wv = tid >> 6;
  const int quad = lane >> 4;
  const int r16 = lane & 15;
  const int rb = wv * 16;

  __shared__ __align__(16) unsigned short Xs[TM * XS];
  __shared__ __align__(16) unsigned short W0t[WID * XS];
  __shared__ __align__(16) unsigned short W1t[WID * HS];
  __shared__ __align__(16) unsigned short W2t[DOUT * HS];
  __shared__ __align__(16) unsigned short Hs[TM * HS];
  __shared__ float sb0[WID];
  __shared__ float sb1[WID];
  __shared__ float sb2[DOUT];
  __shared__ int sid[TM];

  // ---- redundant per-wave count load + shfl inclusive scan: no LDS, no barrier.
  //      Every wave holds pref in registers (one value per lane). ----
  const unsigned c = (unsigned)hist[lane * KEXP + e];
  unsigned p = c;
#pragma unroll
  for (int st = 1; st < NB; st <<= 1) {
    const unsigned v = __shfl_up(p, st, 64);
    if (lane >= st) p += v;
  }
  const int segCnt = __shfl((int)p, NB - 1, 64);
  if ((int)blockIdx.x * TM >= segCnt) return;

  // ---- prefetch tile0 gather chain into registers; overlapped with weight
  //      staging below (issue early, consume after the staging barrier). ----
  int s_pre = 0;
  float4 fA, fB, fC, fD;
  {
    const int t0 = (int)blockIdx.x * TM;
    const int rows = min(TM, segCnt - t0);
    const int pp = t0 + min(lane, rows - 1);
    int local;
    const int sb_ = seg_search(p, c, pp, &local);
    if (lane < rows) {
      s_pre = (int)bucket[(e << 16) + (sb_ << 10) + local];
      if (wv == 0) {
        const float4* fs = (const float4*)(feat + (size_t)s_pre * DOUT);
        fA = fs[0]; fB = fs[1]; fC = fs[2]; fD = fs[3];
      } else if (wv == 1) {
        const float4* fs = (const float4*)(feat + (size_t)s_pre * DOUT);
        fA = fs[4]; fB = fs[5]; fC = fs[6]; fD = fs[7];
      } else if (wv == 2) {
        fA.x = pos[s_pre * 3 + 0];
        fA.y = pos[s_pre * 3 + 1];
        fA.z = pos[s_pre * 3 + 2];
      } else {
        fA.x = view[s_pre * 3 + 0];
        fA.y = view[s_pre * 3 + 1];
        fA.z = view[s_pre * 3 + 2];
      }
    }
  }

  // ---- zero k-padding (NaN-safety: junk bf16 in LDS could be NaN; NaN*0=NaN).
  //      Xs: full zero is safe (consumers are behind the staging barrier).
  //      W0t: zero ONLY pad cols 76..103 — staging writes cols 0..75, so the
  //      write sets are DISJOINT and need no barrier between them (the race
  //      that broke round 1). MFMA reads at most col 95. ----
  for (int i = tid; i < TM * XS; i += 256) Xs[i] = 0;
  for (int g = tid; g < WID * 7; g += 256) {          // 64 rows x 7 uint2 chunks
    const int o = g / 7, ch = g % 7;
    *(uint2*)&W0t[o * XS + 76 + ch * 4] = make_uint2(0u, 0u);
  }

  // ---- stage weights transposed, Wt[o][i] = W[i][o], 4 i per thread ----
  {
    const float* g0 = W0 + (size_t)e * DIN * WID;
    for (int g = tid; g < 19 * WID; g += 256) {        // ceil(74/4)=19 blocks -> cols 0..75
      const int o = g & 63, i4 = g >> 6, ib = i4 * 4;
      unsigned v0 = 0, v1 = 0;
#pragma unroll
      for (int j = 0; j < 4; ++j) {
        const int i = ib + j;
        unsigned short w = (i < DIN) ? f2b(g0[i * WID + o]) : (unsigned short)0;
        if (j < 2) v0 |= (unsigned)w << (16 * j);
        else       v1 |= (unsigned)w << (16 * (j - 2));
      }
      *(uint2*)&W0t[o * XS + ib] = make_uint2(v0, v1);
    }
    const float* g1 = W1 + (size_t)e * WID * WID;
    for (int g = tid; g < 16 * WID; g += 256) {
      const int o = g & 63, i4 = g >> 6, ib = i4 * 4;
      unsigned v0, v1;
      v0 = (unsigned)f2b(g1[(ib + 0) * WID + o]) | ((unsigned)f2b(g1[(ib + 1) * WID + o]) << 16);
      v1 = (unsigned)f2b(g1[(ib + 2) * WID + o]) | ((unsigned)f2b(g1[(ib + 3) * WID + o]) << 16);
      *(uint2*)&W1t[o * HS + ib] = make_uint2(v0, v1);
    }
    const float* g2 = W2 + (size_t)e * WID * DOUT;
    for (int g = tid; g < 16 * DOUT; g += 256) {
      const int o = g & 31, i4 = g >> 5, ib = i4 * 4;
      unsigned v0, v1;
      v0 = (unsigned)f2b(g2[(ib + 0) * DOUT + o]) | ((unsigned)f2b(g2[(ib + 1) * DOUT + o]) << 16);
      v1 = (unsigned)f2b(g2[(ib + 2) * DOUT + o]) | ((unsigned)f2b(g2[(ib + 3) * DOUT + o]) << 16);
      *(uint2*)&W2t[o * HS + ib] = make_uint2(v0, v1);
    }
    if (tid < WID) {
      sb0[tid] = B0[e * WID + tid];
      sb1[tid] = B1[e * WID + tid];
    } else if (tid < WID + DOUT) {
      const int t = tid - WID;
      sb2[t] = B2[e * DOUT + t];
    }
  }
  __syncthreads();

  for (int tile = blockIdx.x; tile * TM < segCnt; tile += GX) {
    const int t0 = tile * TM;
    const int rows = min(TM, segCnt - t0);

    if (tile != (int)blockIdx.x) {
      // rare path (only when segCnt > GX*TM): re-gather for this tile
      __syncthreads();   // protect Xs/sid rebuild vs previous iteration's readers
      const int pp = t0 + min(lane, rows - 1);
      int local;
      const int sb_ = seg_search(p, c, pp, &local);
      if (lane < rows) {
        s_pre = (int)bucket[(e << 16) + (sb_ << 10) + local];
        if (wv == 0) {
          const float4* fs = (const float4*)(feat + (size_t)s_pre * DOUT);
          fA = fs[0]; fB = fs[1]; fC = fs[2]; fD = fs[3];
        } else if (wv == 1) {
          const float4* fs = (const float4*)(feat + (size_t)s_pre * DOUT);
          fA = fs[4]; fB = fs[5]; fC = fs[6]; fD = fs[7];
        } else if (wv == 2) {
          fA.x = pos[s_pre * 3 + 0];
          fA.y = pos[s_pre * 3 + 1];
          fA.z = pos[s_pre * 3 + 2];
        } else {
          fA.x = view[s_pre * 3 + 0];
          fA.y = view[s_pre * 3 + 1];
          fA.z = view[s_pre * 3 + 2];
        }
      }
    }

    // ---- write X tile from registers: row = lane, 4-way split across waves ----
    if (lane < rows) {
      unsigned short* xr = &Xs[lane * XS];
      if (wv == 0) {
        sid[lane] = s_pre;
        xr[0]  = f2b(fA.x); xr[1]  = f2b(fA.y); xr[2]  = f2b(fA.z); xr[3]  = f2b(fA.w);
        xr[4]  = f2b(fB.x); xr[5]  = f2b(fB.y); xr[6]  = f2b(fB.z); xr[7]  = f2b(fB.w);
        xr[8]  = f2b(fC.x); xr[9]  = f2b(fC.y); xr[10] = f2b(fC.z); xr[11] = f2b(fC.w);
        xr[12] = f2b(fD.x); xr[13] = f2b(fD.y); xr[14] = f2b(fD.z); xr[15] = f2b(fD.w);
      } else if (wv == 1) {
        xr[16] = f2b(fA.x); xr[17] = f2b(fA.y); xr[18] = f2b(fA.z); xr[19] = f2b(fA.w);
        xr[20] = f2b(fB.x); xr[21] = f2b(fB.y); xr[22] = f2b(fB.z); xr[23] = f2b(fB.w);
        xr[24] = f2b(fC.x); xr[25] = f2b(fC.y); xr[26] = f2b(fC.z); xr[27] = f2b(fC.w);
        xr[28] = f2b(fD.x); xr[29] = f2b(fD.y); xr[30] = f2b(fD.z); xr[31] = f2b(fD.w);
      } else if (wv == 2) {
        // posenc(positions, deg=2): cols 32..46
        float p3[3] = {fA.x, fA.y, fA.z};
#pragma unroll
        for (int d = 0; d < 3; ++d) xr[32 + d] = f2b(p3[d]);
#pragma unroll
        for (int si = 0; si < 2; ++si) {
          const float sc = (float)(1 << si);
#pragma unroll
          for (int d = 0; d < 3; ++d) {
            const float a = p3[d] * sc;
            xr[35 + si * 3 + d] = f2b(__sinf(a));
            xr[41 + si * 3 + d] = f2b(__cosf(a));
          }
        }
      } else {
        // posenc(viewdirs, deg=4): cols 47..73
        float v3[3] = {fA.x, fA.y, fA.z};
#pragma unroll
        for (int d = 0; d < 3; ++d) xr[47 + d] = f2b(v3[d]);
#pragma unroll
        for (int si = 0; si < 4; ++si) {
          const float sc = (float)(1 << si);
#pragma unroll
          for (int d = 0; d < 3; ++d) {
            const float a = v3[d] * sc;
            xr[50 + si * 3 + d] = f2b(__sinf(a));
            xr[62 + si * 3 + d] = f2b(__cosf(a));
          }
        }
      }
    }
    __syncthreads();

    // ---- layer 0: [64 x 96] @ [96 x 64] -> Hs (relu). Hs rows wave-private. ----
    {
      const short8 a0 = *(const short8*)&Xs[(rb + r16) * XS + 0 + quad * 8];
      const short8 a1 = *(const short8*)&Xs[(rb + r16) * XS + 32 + quad * 8];
      const short8 a2 = *(const short8*)&Xs[(rb + r16) * XS + 64 + quad * 8];
#pragma unroll
      for (int cc = 0; cc < 4; ++cc) {
        const int n0 = cc * 16;
        floatx4 acc = {0.f, 0.f, 0.f, 0.f};
        acc = __builtin_amdgcn_mfma_f32_16x16x32_bf16(
            a0, *(const short8*)&W0t[(n0 + r16) * XS + 0 + quad * 8], acc, 0, 0, 0);
        acc = __builtin_amdgcn_mfma_f32_16x16x32_bf16(
            a1, *(const short8*)&W0t[(n0 + r16) * XS + 32 + quad * 8], acc, 0, 0, 0);
        acc = __builtin_amdgcn_mfma_f32_16x16x32_bf16(
            a2, *(const short8*)&W0t[(n0 + r16) * XS + 64 + quad * 8], acc, 0, 0, 0);
        const float bias = sb0[n0 + r16];
#pragma unroll
        for (int g = 0; g < 4; ++g) {
          const float vv = fmaxf(acc[g] + bias, 0.f);
          Hs[(rb + quad * 4 + g) * HS + n0 + r16] = f2b(vv);
        }
      }
    }

    // ---- layer 1: [64 x 64] @ [64 x 64] -> Hs (relu, wave-private rows) ----
    {
      const short8 h0 = *(const short8*)&Hs[(rb + r16) * HS + 0 + quad * 8];
      const short8 h1 = *(const short8*)&Hs[(rb + r16) * HS + 32 + quad * 8];
#pragma unroll
      for (int cc = 0; cc < 4; ++cc) {
        const int n0 = cc * 16;
        floatx4 acc = {0.f, 0.f, 0.f, 0.f};
        acc = __builtin_amdgcn_mfma_f32_16x16x32_bf16(
            h0, *(const short8*)&W1t[(n0 + r16) * HS + 0 + quad * 8], acc, 0, 0, 0);
        acc = __builtin_amdgcn_mfma_f32_16x16x32_bf16(
            h1, *(const short8*)&W1t[(n0 + r16) * HS + 32 + quad * 8], acc, 0, 0, 0);
        const float bias = sb1[n0 + r16];
#pragma unroll
        for (int g = 0; g < 4; ++g) {
          const float vv = fmaxf(acc[g] + bias, 0.f);
          Hs[(rb + quad * 4 + g) * HS + n0 + r16] = f2b(vv);
        }
      }
    }

    // ---- layer 2: [64 x 64] @ [64 x 32] -> direct f32 global stores ----
    {
      const short8 q0 = *(const short8*)&Hs[(rb + r16) * HS + 0 + quad * 8];
      const short8 q1 = *(const short8*)&Hs[(rb + r16) * HS + 32 + quad * 8];
#pragma unroll
      for (int cc = 0; cc < 2; ++cc) {
        const int n0 = cc * 16;
        floatx4 acc = {0.f, 0.f, 0.f, 0.f};
        acc = __builtin_amdgcn_mfma_f32_16x16x32_bf16(
            q0, *(const short8*)&W2t[(n0 + r16) * HS + 0 + quad * 8], acc, 0, 0, 0);
        acc = __builtin_amdgcn_mfma_f32_16x16x32_bf16(
            q1, *(const short8*)&W2t[(n0 + r16) * HS + 32 + quad * 8], acc, 0, 0, 0);
        const float bias = sb2[n0 + r16];
        const int col = n0 + r16;
#pragma unroll
        for (int g = 0; g < 4; ++g) {
          const int row = rb + quad * 4 + g;
          if (row < rows) {
            out[(size_t)sid[row] * DOUT + col] = acc[g] + bias;
          }
        }
      }
    }
  }
}

extern "C" void kernel_launch(void* const* d_in, const int* in_sizes, int n_in,
                              void* d_out, int out_size, void* d_ws, size_t ws_size,
                              hipStream_t stream) {
  const int* idxs        = (const int*)d_in[0];
  const float* pos       = (const float*)d_in[1];
  const float* view      = (const float*)d_in[2];
  const float* feat      = (const float*)d_in[3];
  const float* W0        = (const float*)d_in[4];
  const float* b0        = (const float*)d_in[5];
  const float* W1        = (const float*)d_in[6];
  const float* b1        = (const float*)d_in[7];
  const float* W2        = (const float*)d_in[8];
  const float* b2        = (const float*)d_in[9];
  float* out             = (float*)d_out;
  unsigned short* bucket = (unsigned short*)d_ws;
  int* hist              = (int*)((char*)d_ws + (size_t)KEXP * NB * 1024 * 2);

  k_scatter<<<NB, 1024, 0, stream>>>(idxs, bucket, hist);
  dim3 grid(GX, KEXP);
  k_mlp<<<grid, 256, 0, stream>>>(hist, bucket, pos, view, feat,
                                  W0, b0, W1, b1, W2, b2, out);
}

// Round 3
// 101.046 us; speedup vs baseline: 1.0756x; 1.0756x over previous
//
#include <hip/hip_runtime.h>
#include <hip/hip_bf16.h>

// Problem constants
#define NS    65536
#define KEXP  8
#define WID   64
#define DOUT  32
#define DIN   74
#define TM    64     // samples per tile
#define XS    104    // X row stride (u16), mult of 8 -> 16B-aligned b128 frags
#define HS    72     // H / W1t / W2t row stride (u16)
#define GX    64     // blocks per expert: 2 tiles/block typical (amortizes staging)
#define NB    64     // scatter blocks (NS/1024)

typedef __attribute__((ext_vector_type(8))) short short8;
typedef __attribute__((ext_vector_type(4))) float floatx4;

// f32 -> bf16 round-to-nearest-even.
__device__ __forceinline__ unsigned short f2b(float f) {
  unsigned u = __builtin_bit_cast(unsigned, f);
  u = u + 0x7FFFu + ((u >> 16) & 1u);
  return (unsigned short)(u >> 16);
}

// d_ws layout:
//   bytes [0 .. 1MB)       : bucket, u16[KEXP][NB][1024] (block-sliced, no init needed)
//   bytes [1MB .. 1MB+2KB) : hist, int[NB][KEXP]         (plain stores, no init needed)
// Memset-free and global-atomic-free: every ws word read was written earlier
// in the same launch (scatter -> mlp graph edge).

__global__ __launch_bounds__(1024) void k_scatter(const int* __restrict__ idxs,
                                                  unsigned short* __restrict__ bucket,
                                                  int* __restrict__ hist) {
  __shared__ int lc[KEXP];
  const int tid = threadIdx.x;
  const int b = blockIdx.x;
  if (tid < KEXP) lc[tid] = 0;
  __syncthreads();
  const int gid = b * 1024 + tid;
  const int e = idxs[gid];
  const int rank = atomicAdd(&lc[e], 1);          // LDS atomic
  bucket[(e << 16) + (b << 10) + rank] = (unsigned short)gid;
  __syncthreads();
  if (tid < KEXP) hist[b * KEXP + tid] = lc[tid];
}

// Binary search over the per-lane-distributed inclusive prefix (p) / counts (c).
// Returns source block sb; *lcl = local rank within that block.
__device__ __forceinline__ int seg_search(unsigned p, unsigned c, int pp, int* lcl) {
  int lo = 0, hi = NB - 1;
#pragma unroll
  for (int it = 0; it < 6; ++it) {
    const int mid = (lo + hi) >> 1;
    const unsigned pm = (unsigned)__shfl((int)p, mid, 64);
    if (pm > (unsigned)pp) hi = mid;
    else lo = mid + 1;
  }
  const unsigned base = (unsigned)__shfl((int)(p - c), lo, 64);  // exclusive prefix of sb
  *lcl = pp - (int)base;
  return lo;
}

__global__ __launch_bounds__(256, 3) void k_mlp(
    const int* __restrict__ hist,
    const unsigned short* __restrict__ bucket,
    const float* __restrict__ pos,
    const float* __restrict__ view,
    const float* __restrict__ feat,
    const float* __restrict__ W0,
    const float* __restrict__ B0,
    const float* __restrict__ W1,
    const float* __restrict__ B1,
    const float* __restrict__ W2,
    const float* __restrict__ B2,
    float* __restrict__ out)
{
  const int e = blockIdx.y;
  const int tid = threadIdx.x;
  const int lane = tid & 63;
  const int wv = tid >> 6;
  const int quad = lane >> 4;
  const int r16 = lane & 15;
  const int rb = wv * 16;

  __shared__ __align__(16) unsigned short Xs[TM * XS];
  __shared__ __align__(16) unsigned short W0t[WID * XS];
  __shared__ __align__(16) unsigned short W1t[WID * HS];
  __shared__ __align__(16) unsigned short W2t[DOUT * HS];
  __shared__ __align__(16) unsigned short Hs[TM * HS];
  __shared__ float sb0[WID];
  __shared__ float sb1[WID];
  __shared__ float sb2[DOUT];
  __shared__ int sid[TM];

  // ---- redundant per-wave count load + shfl inclusive scan: no LDS, no barrier.
  //      Every wave holds pref in registers (one value per lane). ----
  const unsigned c = (unsigned)hist[lane * KEXP + e];
  unsigned p = c;
#pragma unroll
  for (int st = 1; st < NB; st <<= 1) {
    const unsigned v = __shfl_up(p, st, 64);
    if (lane >= st) p += v;
  }
  const int segCnt = __shfl((int)p, NB - 1, 64);
  if ((int)blockIdx.x * TM >= segCnt) return;

  // Register-resident gather state for one tile (consumed at Xs-write).
  int s_pre = 0;
  float4 fA, fB, fC, fD;

  // Gather chain for tile starting at t0: search -> bucket -> feat/pos/view.
  // Registers only, no LDS, no barriers -> safe to issue under compute.
  auto gather = [&](int t0, int rows) {
    const int pp = t0 + min(lane, rows - 1);
    int local;
    const int sb_ = seg_search(p, c, pp, &local);
    if (lane < rows) {
      s_pre = (int)bucket[(e << 16) + (sb_ << 10) + local];
      if (wv == 0) {
        const float4* fs = (const float4*)(feat + (size_t)s_pre * DOUT);
        fA = fs[0]; fB = fs[1]; fC = fs[2]; fD = fs[3];
      } else if (wv == 1) {
        const float4* fs = (const float4*)(feat + (size_t)s_pre * DOUT);
        fA = fs[4]; fB = fs[5]; fC = fs[6]; fD = fs[7];
      } else if (wv == 2) {
        fA.x = pos[s_pre * 3 + 0];
        fA.y = pos[s_pre * 3 + 1];
        fA.z = pos[s_pre * 3 + 2];
      } else {
        fA.x = view[s_pre * 3 + 0];
        fA.y = view[s_pre * 3 + 1];
        fA.z = view[s_pre * 3 + 2];
      }
    }
  };

  // ---- tile-0 gather issued BEFORE weight staging: its ~2 dependent global
  //      loads fly under the staging work below. ----
  {
    const int t0 = (int)blockIdx.x * TM;
    gather(t0, min(TM, segCnt - t0));
  }

  // ---- zero k-padding (NaN-safety: junk bf16 in LDS could be NaN; NaN*0=NaN).
  //      Xs: full zero is safe (consumers are behind the staging barrier).
  //      W0t: zero ONLY pad cols 76..103 — staging writes cols 0..75, so the
  //      write sets are DISJOINT and need no barrier between them. MFMA reads
  //      at most col 95. ----
  for (int i = tid; i < TM * XS; i += 256) Xs[i] = 0;
  for (int g = tid; g < WID * 7; g += 256) {          // 64 rows x 7 uint2 chunks
    const int o = g / 7, ch = g % 7;
    *(uint2*)&W0t[o * XS + 76 + ch * 4] = make_uint2(0u, 0u);
  }

  // ---- stage weights transposed, Wt[o][i] = W[i][o], 4 i per thread ----
  {
    const float* g0 = W0 + (size_t)e * DIN * WID;
    for (int g = tid; g < 19 * WID; g += 256) {        // ceil(74/4)=19 blocks -> cols 0..75
      const int o = g & 63, i4 = g >> 6, ib = i4 * 4;
      unsigned v0 = 0, v1 = 0;
#pragma unroll
      for (int j = 0; j < 4; ++j) {
        const int i = ib + j;
        unsigned short w = (i < DIN) ? f2b(g0[i * WID + o]) : (unsigned short)0;
        if (j < 2) v0 |= (unsigned)w << (16 * j);
        else       v1 |= (unsigned)w << (16 * (j - 2));
      }
      *(uint2*)&W0t[o * XS + ib] = make_uint2(v0, v1);
    }
    const float* g1 = W1 + (size_t)e * WID * WID;
    for (int g = tid; g < 16 * WID; g += 256) {
      const int o = g & 63, i4 = g >> 6, ib = i4 * 4;
      unsigned v0, v1;
      v0 = (unsigned)f2b(g1[(ib + 0) * WID + o]) | ((unsigned)f2b(g1[(ib + 1) * WID + o]) << 16);
      v1 = (unsigned)f2b(g1[(ib + 2) * WID + o]) | ((unsigned)f2b(g1[(ib + 3) * WID + o]) << 16);
      *(uint2*)&W1t[o * HS + ib] = make_uint2(v0, v1);
    }
    const float* g2 = W2 + (size_t)e * WID * DOUT;
    for (int g = tid; g < 16 * DOUT; g += 256) {
      const int o = g & 31, i4 = g >> 5, ib = i4 * 4;
      unsigned v0, v1;
      v0 = (unsigned)f2b(g2[(ib + 0) * DOUT + o]) | ((unsigned)f2b(g2[(ib + 1) * DOUT + o]) << 16);
      v1 = (unsigned)f2b(g2[(ib + 2) * DOUT + o]) | ((unsigned)f2b(g2[(ib + 3) * DOUT + o]) << 16);
      *(uint2*)&W2t[o * HS + ib] = make_uint2(v0, v1);
    }
    if (tid < WID) {
      sb0[tid] = B0[e * WID + tid];
      sb1[tid] = B1[e * WID + tid];
    } else if (tid < WID + DOUT) {
      const int t = tid - WID;
      sb2[t] = B2[e * DOUT + t];
    }
  }
  __syncthreads();

  for (int tile = blockIdx.x; tile * TM < segCnt; tile += GX) {
    const int t0 = tile * TM;
    const int rows = min(TM, segCnt - t0);

    if (tile != (int)blockIdx.x) {
      __syncthreads();   // protect Xs/sid rebuild vs previous iteration's readers
    }

    // ---- write X tile from registers: row = lane, 4-way split across waves ----
    if (lane < rows) {
      unsigned short* xr = &Xs[lane * XS];
      if (wv == 0) {
        sid[lane] = s_pre;
        xr[0]  = f2b(fA.x); xr[1]  = f2b(fA.y); xr[2]  = f2b(fA.z); xr[3]  = f2b(fA.w);
        xr[4]  = f2b(fB.x); xr[5]  = f2b(fB.y); xr[6]  = f2b(fB.z); xr[7]  = f2b(fB.w);
        xr[8]  = f2b(fC.x); xr[9]  = f2b(fC.y); xr[10] = f2b(fC.z); xr[11] = f2b(fC.w);
        xr[12] = f2b(fD.x); xr[13] = f2b(fD.y); xr[14] = f2b(fD.z); xr[15] = f2b(fD.w);
      } else if (wv == 1) {
        xr[16] = f2b(fA.x); xr[17] = f2b(fA.y); xr[18] = f2b(fA.z); xr[19] = f2b(fA.w);
        xr[20] = f2b(fB.x); xr[21] = f2b(fB.y); xr[22] = f2b(fB.z); xr[23] = f2b(fB.w);
        xr[24] = f2b(fC.x); xr[25] = f2b(fC.y); xr[26] = f2b(fC.z); xr[27] = f2b(fC.w);
        xr[28] = f2b(fD.x); xr[29] = f2b(fD.y); xr[30] = f2b(fD.z); xr[31] = f2b(fD.w);
      } else if (wv == 2) {
        // posenc(positions, deg=2): cols 32..46
        float p3[3] = {fA.x, fA.y, fA.z};
#pragma unroll
        for (int d = 0; d < 3; ++d) xr[32 + d] = f2b(p3[d]);
#pragma unroll
        for (int si = 0; si < 2; ++si) {
          const float sc = (float)(1 << si);
#pragma unroll
          for (int d = 0; d < 3; ++d) {
            const float a = p3[d] * sc;
            xr[35 + si * 3 + d] = f2b(__sinf(a));
            xr[41 + si * 3 + d] = f2b(__cosf(a));
          }
        }
      } else {
        // posenc(viewdirs, deg=4): cols 47..73
        float v3[3] = {fA.x, fA.y, fA.z};
#pragma unroll
        for (int d = 0; d < 3; ++d) xr[47 + d] = f2b(v3[d]);
#pragma unroll
        for (int si = 0; si < 4; ++si) {
          const float sc = (float)(1 << si);
#pragma unroll
          for (int d = 0; d < 3; ++d) {
            const float a = v3[d] * sc;
            xr[50 + si * 3 + d] = f2b(__sinf(a));
            xr[62 + si * 3 + d] = f2b(__cosf(a));
          }
        }
      }
    }
    __syncthreads();

    // ---- software pipeline: issue NEXT tile's gather chain now (registers
    //      only, no LDS) so its dependent global loads fly under the MFMA +
    //      LDS compute below instead of sitting exposed between barriers. ----
    {
      const int nt0 = t0 + GX * TM;
      if (nt0 < segCnt) gather(nt0, min(TM, segCnt - nt0));
    }

    // ---- layer 0: [64 x 96] @ [96 x 64] -> Hs (relu). Hs rows wave-private. ----
    {
      const short8 a0 = *(const short8*)&Xs[(rb + r16) * XS + 0 + quad * 8];
      const short8 a1 = *(const short8*)&Xs[(rb + r16) * XS + 32 + quad * 8];
      const short8 a2 = *(const short8*)&Xs[(rb + r16) * XS + 64 + quad * 8];
#pragma unroll
      for (int cc = 0; cc < 4; ++cc) {
        const int n0 = cc * 16;
        floatx4 acc = {0.f, 0.f, 0.f, 0.f};
        acc = __builtin_amdgcn_mfma_f32_16x16x32_bf16(
            a0, *(const short8*)&W0t[(n0 + r16) * XS + 0 + quad * 8], acc, 0, 0, 0);
        acc = __builtin_amdgcn_mfma_f32_16x16x32_bf16(
            a1, *(const short8*)&W0t[(n0 + r16) * XS + 32 + quad * 8], acc, 0, 0, 0);
        acc = __builtin_amdgcn_mfma_f32_16x16x32_bf16(
            a2, *(const short8*)&W0t[(n0 + r16) * XS + 64 + quad * 8], acc, 0, 0, 0);
        const float bias = sb0[n0 + r16];
#pragma unroll
        for (int g = 0; g < 4; ++g) {
          const float vv = fmaxf(acc[g] + bias, 0.f);
          Hs[(rb + quad * 4 + g) * HS + n0 + r16] = f2b(vv);
        }
      }
    }

    // ---- layer 1: [64 x 64] @ [64 x 64] -> Hs (relu, wave-private rows) ----
    {
      const short8 h0 = *(const short8*)&Hs[(rb + r16) * HS + 0 + quad * 8];
      const short8 h1 = *(const short8*)&Hs[(rb + r16) * HS + 32 + quad * 8];
#pragma unroll
      for (int cc = 0; cc < 4; ++cc) {
        const int n0 = cc * 16;
        floatx4 acc = {0.f, 0.f, 0.f, 0.f};
        acc = __builtin_amdgcn_mfma_f32_16x16x32_bf16(
            h0, *(const short8*)&W1t[(n0 + r16) * HS + 0 + quad * 8], acc, 0, 0, 0);
        acc = __builtin_amdgcn_mfma_f32_16x16x32_bf16(
            h1, *(const short8*)&W1t[(n0 + r16) * HS + 32 + quad * 8], acc, 0, 0, 0);
        const float bias = sb1[n0 + r16];
#pragma unroll
        for (int g = 0; g < 4; ++g) {
          const float vv = fmaxf(acc[g] + bias, 0.f);
          Hs[(rb + quad * 4 + g) * HS + n0 + r16] = f2b(vv);
        }
      }
    }

    // ---- layer 2: [64 x 64] @ [64 x 32] -> direct f32 global stores ----
    {
      const short8 q0 = *(const short8*)&Hs[(rb + r16) * HS + 0 + quad * 8];
      const short8 q1 = *(const short8*)&Hs[(rb + r16) * HS + 32 + quad * 8];
#pragma unroll
      for (int cc = 0; cc < 2; ++cc) {
        const int n0 = cc * 16;
        floatx4 acc = {0.f, 0.f, 0.f, 0.f};
        acc = __builtin_amdgcn_mfma_f32_16x16x32_bf16(
            q0, *(const short8*)&W2t[(n0 + r16) * HS + 0 + quad * 8], acc, 0, 0, 0);
        acc = __builtin_amdgcn_mfma_f32_16x16x32_bf16(
            q1, *(const short8*)&W2t[(n0 + r16) * HS + 32 + quad * 8], acc, 0, 0, 0);
        const float bias = sb2[n0 + r16];
        const int col = n0 + r16;
#pragma unroll
        for (int g = 0; g < 4; ++g) {
          const int row = rb + quad * 4 + g;
          if (row < rows) {
            out[(size_t)sid[row] * DOUT + col] = acc[g] + bias;
          }
        }
      }
    }
  }
}

extern "C" void kernel_launch(void* const* d_in, const int* in_sizes, int n_in,
                              void* d_out, int out_size, void* d_ws, size_t ws_size,
                              hipStream_t stream) {
  const int* idxs        = (const int*)d_in[0];
  const float* pos       = (const float*)d_in[1];
  const float* view      = (const float*)d_in[2];
  const float* feat      = (const float*)d_in[3];
  const float* W0        = (const float*)d_in[4];
  const float* b0        = (const float*)d_in[5];
  const float* W1        = (const float*)d_in[6];
  const float* b1        = (const float*)d_in[7];
  const float* W2        = (const float*)d_in[8];
  const float* b2        = (const float*)d_in[9];
  float* out             = (float*)d_out;
  unsigned short* bucket = (unsigned short*)d_ws;
  int* hist              = (int*)((char*)d_ws + (size_t)KEXP * NB * 1024 * 2);

  k_scatter<<<NB, 1024, 0, stream>>>(idxs, bucket, hist);
  dim3 grid(GX, KEXP);
  k_mlp<<<grid, 256, 0, stream>>>(hist, bucket, pos, view, feat,
                                  W0, b0, W1, b1, W2, b2, out);
}